// Round 1
// baseline (1080.470 us; speedup 1.0000x reference)
//
#include <hip/hip_runtime.h>

#define NN 2048
#define EE 65536
#define BB 8
#define EPSF 1e-5f

typedef __attribute__((ext_vector_type(4))) float f32x4;
typedef __attribute__((ext_vector_type(8))) short short8;
typedef __attribute__((ext_vector_type(4))) unsigned short u16x4;

__device__ inline unsigned short f2bf(float f) {
    unsigned u = __float_as_uint(f);
    unsigned r = (u + 0x7fffu + ((u >> 16) & 1u)) >> 16;   // RNE
    return (unsigned short)r;
}

// ---------------- graph build ----------------
__global__ void zero_i32(int* p, int n) {
    int i = blockIdx.x * 256 + threadIdx.x;
    if (i < n) p[i] = 0;
}
__global__ void zero_f32(float* p, int n) {
    int i = blockIdx.x * 256 + threadIdx.x;
    if (i < n) p[i] = 0.f;
}

__global__ void count_kernel(const int* __restrict__ ei, int* __restrict__ counts) {
    int e = blockIdx.x * 256 + threadIdx.x;
    if (e < EE + NN) {
        int d = (e < EE) ? ei[EE + e] : (e - EE);
        atomicAdd(&counts[d], 1);
    }
}

__global__ void dinv_kernel(const int* __restrict__ counts, float* __restrict__ dinv) {
    int i = blockIdx.x * 256 + threadIdx.x;
    if (i < NN) dinv[i] = rsqrtf((float)counts[i]);
}

// single block, 256 threads, 8 counts each -> exclusive scan into row_ptr[0..NN]
__global__ void scan_kernel(const int* __restrict__ counts, int* __restrict__ row_ptr) {
    __shared__ int sh[256];
    int tid = threadIdx.x;
    int loc[8];
    int run = 0;
#pragma unroll
    for (int i = 0; i < 8; ++i) { loc[i] = run; run += counts[tid * 8 + i]; }
    sh[tid] = run;
    __syncthreads();
    for (int off = 1; off < 256; off <<= 1) {
        int v = (tid >= off) ? sh[tid - off] : 0;
        __syncthreads();
        sh[tid] += v;
        __syncthreads();
    }
    int excl = sh[tid] - run;
#pragma unroll
    for (int i = 0; i < 8; ++i) row_ptr[tid * 8 + i] = excl + loc[i];
    if (tid == 255) row_ptr[NN] = excl + run;
}

__global__ void fill_kernel(const int* __restrict__ ei, const float* __restrict__ dinv,
                            const int* __restrict__ row_ptr, int* __restrict__ fillc,
                            int* __restrict__ colA, float* __restrict__ valA) {
    int e = blockIdx.x * 256 + threadIdx.x;
    if (e < EE + NN) {
        int s, d;
        if (e < EE) { s = ei[e]; d = ei[EE + e]; }
        else        { s = d = e - EE; }
        int pos = row_ptr[d] + atomicAdd(&fillc[d], 1);
        colA[pos] = s;
        valA[pos] = dinv[s] * dinv[d];
    }
}

__global__ void rowsum_kernel(const int* __restrict__ row_ptr, const float* __restrict__ valA,
                              float* __restrict__ R) {
    int d = blockIdx.x * 256 + threadIdx.x;
    if (d < NN) {
        float s = 0.f;
        for (int j = row_ptr[d]; j < row_ptr[d + 1]; ++j) s += valA[j];
        R[d] = s;
    }
}

__global__ void conv_bf16(const float* __restrict__ src, unsigned short* __restrict__ dst, int n) {
    int i = blockIdx.x * 256 + threadIdx.x;
    if (i < n) dst[i] = f2bf(src[i]);
}

// ---------------- aggregation (CSR gather SpMM), BN affine folded in ----------------
// Aout[b][dst][f] (bf16) = s[b][f] * sum_j val[j]*Yin[b][col[j]][f] + t[b][f]*R[dst]
template <int TPD>
__global__ __launch_bounds__(256) void agg_kernel(
    const float* __restrict__ Yin, const int* __restrict__ row_ptr,
    const int* __restrict__ colA, const float* __restrict__ valA,
    const float* __restrict__ rowsumR, const float* __restrict__ s_arr,
    const float* __restrict__ t_arr, unsigned short* __restrict__ Aout, int F) {
    constexpr int DPB = 256 / TPD;
    int b = blockIdx.y;
    int dst = blockIdx.x * DPB + threadIdx.x / TPD;
    int lane = threadIdx.x % TPD;
    const f32x4* Yb = (const f32x4*)(Yin + (size_t)b * NN * F);
    int beg = row_ptr[dst], end = row_ptr[dst + 1];
    f32x4 acc = {0.f, 0.f, 0.f, 0.f};
    for (int j = beg; j < end; ++j) {
        int c = colA[j];
        float v = valA[j];
        f32x4 y = Yb[(size_t)c * (F / 4) + lane];
        acc += v * y;
    }
    f32x4 o;
    if (s_arr) {
        f32x4 s = ((const f32x4*)(s_arr + b * F))[lane];
        f32x4 t = ((const f32x4*)(t_arr + b * F))[lane];
        o = s * acc + t * rowsumR[dst];
    } else {
        o = acc;
    }
    u16x4 ob = {f2bf(o[0]), f2bf(o[1]), f2bf(o[2]), f2bf(o[3])};
    *(u16x4*)(Aout + (size_t)b * NN * F + (size_t)dst * F + lane * 4) = ob;
}

// ---------------- bf16 MFMA GEMM: Y = A @ W^T + bias, leaky-relu epilogue ----------------
// A [R,K] bf16, W [F,K] bf16 (both K-contiguous), Y [R,F] f32. R,F mult of 128, K mult of 32.
__global__ __launch_bounds__(256) void gemm_bias_lrelu(
    const unsigned short* __restrict__ A, const unsigned short* __restrict__ W,
    const float* __restrict__ bias, float* __restrict__ Y, int K, int F) {
    __shared__ unsigned short lds_a[128 * 32];
    __shared__ unsigned short lds_b[128 * 32];
    const int tid = threadIdx.x;
    const int row0 = blockIdx.x * 128;
    const int col0 = blockIdx.y * 128;
    const int wave = tid >> 6;
    const int lane = tid & 63;
    const int wr = (wave >> 1) * 64;
    const int wc = (wave & 1) * 64;
    const int lrow = lane & 15;
    const int q = lane >> 4;

    f32x4 acc[4][4] = {};

    const int srow = tid >> 2;  // 0..63
    const int skg = tid & 3;    // k-group

    for (int k0 = 0; k0 < K; k0 += 32) {
#pragma unroll
        for (int half = 0; half < 2; ++half) {
            int r = srow + half * 64;
            short8 va = *(const short8*)(A + (size_t)(row0 + r) * K + k0 + skg * 8);
            short8 vb = *(const short8*)(W + (size_t)(col0 + r) * K + k0 + skg * 8);
            int kga = skg ^ ((r >> 1) & 3);  // xor-swizzle: 2-way (free) LDS conflicts
            *(short8*)(lds_a + r * 32 + kga * 8) = va;
            *(short8*)(lds_b + r * 32 + kga * 8) = vb;
        }
        __syncthreads();
        short8 af[4], bf[4];
#pragma unroll
        for (int mt = 0; mt < 4; ++mt) {
            int r = wr + mt * 16 + lrow;
            int kg = q ^ ((r >> 1) & 3);
            af[mt] = *(const short8*)(lds_a + r * 32 + kg * 8);
        }
#pragma unroll
        for (int nt = 0; nt < 4; ++nt) {
            int r = wc + nt * 16 + lrow;
            int kg = q ^ ((r >> 1) & 3);
            bf[nt] = *(const short8*)(lds_b + r * 32 + kg * 8);
        }
#pragma unroll
        for (int mt = 0; mt < 4; ++mt)
#pragma unroll
            for (int nt = 0; nt < 4; ++nt)
                acc[mt][nt] = __builtin_amdgcn_mfma_f32_16x16x32_bf16(af[mt], bf[nt], acc[mt][nt], 0, 0, 0);
        __syncthreads();
    }
    // epilogue: C/D layout col=lane&15, row=q*4+reg
#pragma unroll
    for (int nt = 0; nt < 4; ++nt) {
        int col = col0 + wc + nt * 16 + lrow;
        float bv = bias[col];
#pragma unroll
        for (int mt = 0; mt < 4; ++mt) {
#pragma unroll
            for (int reg = 0; reg < 4; ++reg) {
                int row = row0 + wr + mt * 16 + q * 4 + reg;
                float v = acc[mt][nt][reg] + bv;
                v = (v > 0.f) ? v : 0.01f * v;
                Y[(size_t)row * F + col] = v;
            }
        }
    }
}

// ---------------- batchnorm stats ----------------
__global__ __launch_bounds__(256) void bn_partial(const float* __restrict__ Y,
                                                  float* __restrict__ sum, float* __restrict__ sq, int F) {
    int c = blockIdx.x * 256 + threadIdx.x;
    int b = blockIdx.y;
    int n0 = blockIdx.z * 128;
    const float* p = Y + ((size_t)b * NN + n0) * F + c;
    float s = 0.f, s2 = 0.f;
#pragma unroll 4
    for (int i = 0; i < 128; ++i) {
        float v = p[(size_t)i * F];
        s += v;
        s2 += v * v;
    }
    atomicAdd(&sum[b * F + c], s);
    atomicAdd(&sq[b * F + c], s2);
}

__global__ void bn_finalize(const float* __restrict__ sum, const float* __restrict__ sq,
                            const float* __restrict__ g, const float* __restrict__ be,
                            float* __restrict__ s_arr, float* __restrict__ t_arr, int F) {
    int i = blockIdx.x * 256 + threadIdx.x;
    if (i >= BB * F) return;
    int c = i % F;
    float mu = sum[i] * (1.f / NN);
    float var = sq[i] * (1.f / NN) - mu * mu;
    float rs = rsqrtf(var + EPSF);
    float sc = g[c] * rs;
    s_arr[i] = sc;
    t_arr[i] = be[c] - mu * sc;
}

// ---------------- final layernorm over 1024 channels per (b,n) ----------------
__global__ __launch_bounds__(256) void final_ln(const float* __restrict__ Y,
                                                const float* __restrict__ s_arr, const float* __restrict__ t_arr,
                                                const float* __restrict__ lng, const float* __restrict__ lnb,
                                                float* __restrict__ out) {
    int bn = blockIdx.x;
    int b = bn >> 11;
    int tid = threadIdx.x;
    f32x4 h = ((const f32x4*)(Y + (size_t)bn * 1024))[tid];
    f32x4 sv = ((const f32x4*)(s_arr + b * 1024))[tid];
    f32x4 tv = ((const f32x4*)(t_arr + b * 1024))[tid];
    h = sv * h + tv;  // apply layer-5 BN
    float s = h[0] + h[1] + h[2] + h[3];
    float s2 = h[0] * h[0] + h[1] * h[1] + h[2] * h[2] + h[3] * h[3];
#pragma unroll
    for (int off = 32; off; off >>= 1) {
        s += __shfl_down(s, off);
        s2 += __shfl_down(s2, off);
    }
    __shared__ float ssum[4], ssq[4];
    int wv = tid >> 6, ln = tid & 63;
    if (ln == 0) { ssum[wv] = s; ssq[wv] = s2; }
    __syncthreads();
    if (tid == 0) {
        float S = ssum[0] + ssum[1] + ssum[2] + ssum[3];
        float Q = ssq[0] + ssq[1] + ssq[2] + ssq[3];
        float mu = S * (1.f / 1024.f);
        float var = Q * (1.f / 1024.f) - mu * mu;
        ssum[0] = mu;
        ssq[0] = rsqrtf(var + EPSF);
    }
    __syncthreads();
    float mu = ssum[0], rs = ssq[0];
    f32x4 gv = ((const f32x4*)lng)[tid];
    f32x4 bv = ((const f32x4*)lnb)[tid];
    f32x4 o = (h - mu) * rs * gv + bv;
    ((f32x4*)(out + (size_t)bn * 1024))[tid] = o;
}

// ---------------- host ----------------
extern "C" void kernel_launch(void* const* d_in, const int* in_sizes, int n_in,
                              void* d_out, int out_size, void* d_ws, size_t ws_size,
                              hipStream_t stream) {
    const float* w[5]    = {(const float*)d_in[0], (const float*)d_in[4], (const float*)d_in[8],
                            (const float*)d_in[12], (const float*)d_in[16]};
    const float* bias[5] = {(const float*)d_in[1], (const float*)d_in[5], (const float*)d_in[9],
                            (const float*)d_in[13], (const float*)d_in[17]};
    const float* gam[5]  = {(const float*)d_in[2], (const float*)d_in[6], (const float*)d_in[10],
                            (const float*)d_in[14], (const float*)d_in[18]};
    const float* bet[5]  = {(const float*)d_in[3], (const float*)d_in[7], (const float*)d_in[11],
                            (const float*)d_in[15], (const float*)d_in[19]};
    const float* ln_g = (const float*)d_in[20];
    const float* ln_b = (const float*)d_in[21];
    const float* x    = (const float*)d_in[22];
    const int* ei     = (const int*)d_in[23];

    char* p = (char*)d_ws;
    auto alloc = [&](size_t bytes) {
        char* r = p;
        p += (bytes + 255) & ~(size_t)255;
        return r;
    };
    float* dinv    = (float*)alloc(NN * 4);
    float* rowsumR = (float*)alloc(NN * 4);
    int* row_ptr   = (int*)alloc((NN + 1) * 4);
    int* counts    = (int*)alloc(NN * 4);
    int* fillc     = (int*)alloc(NN * 4);
    int* colA      = (int*)alloc((size_t)(EE + NN) * 4);
    float* valA    = (float*)alloc((size_t)(EE + NN) * 4);
    float* bnsum   = (float*)alloc((size_t)BB * 1024 * 4);
    float* bnsq    = (float*)alloc((size_t)BB * 1024 * 4);
    float* s_arr   = (float*)alloc((size_t)BB * 1024 * 4);
    float* t_arr   = (float*)alloc((size_t)BB * 1024 * 4);
    const int wsz[5] = {256 * 64, 512 * 256, 1024 * 512, 1024 * 1024, 1024 * 1024};
    unsigned short* wbf[5];
    for (int i = 0; i < 5; ++i) wbf[i] = (unsigned short*)alloc((size_t)wsz[i] * 2);
    unsigned short* bufA = (unsigned short*)alloc((size_t)BB * NN * 1024 * 2);
    float* bufY          = (float*)alloc((size_t)BB * NN * 1024 * 4);

    // graph build (once per call; CSR shared across batch & layers)
    zero_i32<<<(NN + 255) / 256, 256, 0, stream>>>(counts, NN);
    zero_i32<<<(NN + 255) / 256, 256, 0, stream>>>(fillc, NN);
    count_kernel<<<(EE + NN + 255) / 256, 256, 0, stream>>>(ei, counts);
    dinv_kernel<<<(NN + 255) / 256, 256, 0, stream>>>(counts, dinv);
    scan_kernel<<<1, 256, 0, stream>>>(counts, row_ptr);
    fill_kernel<<<(EE + NN + 255) / 256, 256, 0, stream>>>(ei, dinv, row_ptr, fillc, colA, valA);
    rowsum_kernel<<<(NN + 255) / 256, 256, 0, stream>>>(row_ptr, valA, rowsumR);

    for (int i = 0; i < 5; ++i)
        conv_bf16<<<(wsz[i] + 255) / 256, 256, 0, stream>>>(w[i], wbf[i], wsz[i]);

    const int Kin[5]  = {64, 256, 512, 1024, 1024};
    const int Fout[5] = {256, 512, 1024, 1024, 1024};
    const float* aggIn = x;
    for (int l = 0; l < 5; ++l) {
        int K = Kin[l], F = Fout[l];
        const float* sa = (l == 0) ? nullptr : s_arr;
        const float* ta = (l == 0) ? nullptr : t_arr;
        switch (K) {
            case 64:
                agg_kernel<16><<<dim3(NN / 16, BB), 256, 0, stream>>>(aggIn, row_ptr, colA, valA, rowsumR, sa, ta, bufA, K);
                break;
            case 256:
                agg_kernel<64><<<dim3(NN / 4, BB), 256, 0, stream>>>(aggIn, row_ptr, colA, valA, rowsumR, sa, ta, bufA, K);
                break;
            case 512:
                agg_kernel<128><<<dim3(NN / 2, BB), 256, 0, stream>>>(aggIn, row_ptr, colA, valA, rowsumR, sa, ta, bufA, K);
                break;
            default:
                agg_kernel<256><<<dim3(NN, BB), 256, 0, stream>>>(aggIn, row_ptr, colA, valA, rowsumR, sa, ta, bufA, K);
                break;
        }
        gemm_bias_lrelu<<<dim3(BB * NN / 128, F / 128), 256, 0, stream>>>(bufA, wbf[l], bias[l], bufY, K, F);
        zero_f32<<<(BB * 1024 + 255) / 256, 256, 0, stream>>>(bnsum, BB * 1024);
        zero_f32<<<(BB * 1024 + 255) / 256, 256, 0, stream>>>(bnsq, BB * 1024);
        bn_partial<<<dim3(F / 256, BB, 16), 256, 0, stream>>>(bufY, bnsum, bnsq, F);
        bn_finalize<<<(BB * F + 255) / 256, 256, 0, stream>>>(bnsum, bnsq, gam[l], bet[l], s_arr, t_arr, F);
        aggIn = bufY;
    }
    final_ln<<<BB * NN, 256, 0, stream>>>(bufY, s_arr, t_arr, ln_g, ln_b, (float*)d_out);
}

// Round 2
// 703.253 us; speedup vs baseline: 1.5364x; 1.5364x over previous
//
#include <hip/hip_runtime.h>

#define NN 2048
#define EE 65536
#define BB 8
#define EPSF 1e-5f

typedef __attribute__((ext_vector_type(4))) float f32x4;
typedef __attribute__((ext_vector_type(8))) short short8;
typedef __attribute__((ext_vector_type(4))) unsigned short u16x4;

__device__ inline unsigned short f2bf(float f) {
    unsigned u = __float_as_uint(f);
    unsigned r = (u + 0x7fffu + ((u >> 16) & 1u)) >> 16;   // RNE
    return (unsigned short)r;
}
__device__ inline float bf2f(unsigned short u) {
    return __uint_as_float(((unsigned)u) << 16);
}

// async global->LDS, 16B per lane; lds dest = wave-uniform base + lane*16
__device__ inline void gload16(const unsigned short* g, unsigned short* l) {
    __builtin_amdgcn_global_load_lds(
        (const __attribute__((address_space(1))) void*)g,
        (__attribute__((address_space(3))) void*)l, 16, 0, 0);
}

// ---------------- graph build ----------------
__global__ void zero_i32(int* p, int n) {
    int i = blockIdx.x * 256 + threadIdx.x;
    if (i < n) p[i] = 0;
}
__global__ void zero_f32(float* p, int n) {
    int i = blockIdx.x * 256 + threadIdx.x;
    if (i < n) p[i] = 0.f;
}

__global__ void count_kernel(const int* __restrict__ ei, int* __restrict__ counts) {
    int e = blockIdx.x * 256 + threadIdx.x;
    if (e < EE + NN) {
        int d = (e < EE) ? ei[EE + e] : (e - EE);
        atomicAdd(&counts[d], 1);
    }
}

__global__ void dinv_kernel(const int* __restrict__ counts, float* __restrict__ dinv) {
    int i = blockIdx.x * 256 + threadIdx.x;
    if (i < NN) dinv[i] = rsqrtf((float)counts[i]);
}

__global__ void scan_kernel(const int* __restrict__ counts, int* __restrict__ row_ptr) {
    __shared__ int sh[256];
    int tid = threadIdx.x;
    int loc[8];
    int run = 0;
#pragma unroll
    for (int i = 0; i < 8; ++i) { loc[i] = run; run += counts[tid * 8 + i]; }
    sh[tid] = run;
    __syncthreads();
    for (int off = 1; off < 256; off <<= 1) {
        int v = (tid >= off) ? sh[tid - off] : 0;
        __syncthreads();
        sh[tid] += v;
        __syncthreads();
    }
    int excl = sh[tid] - run;
#pragma unroll
    for (int i = 0; i < 8; ++i) row_ptr[tid * 8 + i] = excl + loc[i];
    if (tid == 255) row_ptr[NN] = excl + run;
}

__global__ void fill_kernel(const int* __restrict__ ei, const float* __restrict__ dinv,
                            const int* __restrict__ row_ptr, int* __restrict__ fillc,
                            int* __restrict__ colA, float* __restrict__ valA) {
    int e = blockIdx.x * 256 + threadIdx.x;
    if (e < EE + NN) {
        int s, d;
        if (e < EE) { s = ei[e]; d = ei[EE + e]; }
        else        { s = d = e - EE; }
        int pos = row_ptr[d] + atomicAdd(&fillc[d], 1);
        colA[pos] = s;
        valA[pos] = dinv[s] * dinv[d];
    }
}

__global__ void rowsum_kernel(const int* __restrict__ row_ptr, const float* __restrict__ valA,
                              float* __restrict__ R) {
    int d = blockIdx.x * 256 + threadIdx.x;
    if (d < NN) {
        float s = 0.f;
        for (int j = row_ptr[d]; j < row_ptr[d + 1]; ++j) s += valA[j];
        R[d] = s;
    }
}

__global__ void conv_bf16(const float* __restrict__ src, unsigned short* __restrict__ dst, int n) {
    int i = blockIdx.x * 256 + threadIdx.x;
    if (i < n) dst[i] = f2bf(src[i]);
}

// ---------------- aggregation, layer 1 (f32 input x, F=64) ----------------
// grid.x = (NN/DPB)*8, graph = blockIdx.x & 7 (XCD pin)
__global__ __launch_bounds__(256) void agg_f32(
    const float* __restrict__ Yin, const int* __restrict__ row_ptr,
    const int* __restrict__ colA, const float* __restrict__ valA,
    unsigned short* __restrict__ Aout) {
    constexpr int TPD = 16, DPB = 16, F = 64;
    int b = blockIdx.x & 7;
    int dst = (blockIdx.x >> 3) * DPB + threadIdx.x / TPD;
    int lane = threadIdx.x % TPD;
    const f32x4* Yb = (const f32x4*)(Yin + (size_t)b * NN * F);
    int beg = row_ptr[dst], end = row_ptr[dst + 1];
    f32x4 acc = {0.f, 0.f, 0.f, 0.f};
    for (int j = beg; j < end; ++j) {
        int c = colA[j];
        float v = valA[j];
        acc += v * Yb[(size_t)c * (F / 4) + lane];
    }
    u16x4 ob = {f2bf(acc[0]), f2bf(acc[1]), f2bf(acc[2]), f2bf(acc[3])};
    *(u16x4*)(Aout + (size_t)b * NN * F + (size_t)dst * F + lane * 4) = ob;
}

// ---------------- aggregation, layers 2..5 (bf16 Y, BN affine folded) ----------------
// Aout[b][dst][f] = s[b][f] * sum_j val[j]*Y[b][col[j]][f] + t[b][f]*R[dst]
// TPD threads per dst, 8 bf16 features per thread. grid.x = (NN/DPB)*8, graph = blockIdx.x&7.
template <int TPD>
__global__ __launch_bounds__(256) void agg_bf16(
    const unsigned short* __restrict__ Yin, const int* __restrict__ row_ptr,
    const int* __restrict__ colA, const float* __restrict__ valA,
    const float* __restrict__ rowsumR, const float* __restrict__ s_arr,
    const float* __restrict__ t_arr, unsigned short* __restrict__ Aout, int F) {
    constexpr int DPB = 256 / TPD;
    int b = blockIdx.x & 7;
    int dst = (blockIdx.x >> 3) * DPB + threadIdx.x / TPD;
    int lane = threadIdx.x % TPD;
    const unsigned short* Yb = Yin + (size_t)b * NN * F;
    int beg = row_ptr[dst], end = row_ptr[dst + 1];
    float acc[8] = {};
    for (int j = beg; j < end; ++j) {
        int c = colA[j];
        float v = valA[j];
        short8 y = *(const short8*)(Yb + (size_t)c * F + lane * 8);
#pragma unroll
        for (int k = 0; k < 8; ++k) acc[k] += v * bf2f((unsigned short)y[k]);
    }
    float R = rowsumR[dst];
    f32x4 s0 = ((const f32x4*)(s_arr + b * F))[lane * 2];
    f32x4 s1 = ((const f32x4*)(s_arr + b * F))[lane * 2 + 1];
    f32x4 t0 = ((const f32x4*)(t_arr + b * F))[lane * 2];
    f32x4 t1 = ((const f32x4*)(t_arr + b * F))[lane * 2 + 1];
    unsigned short ob[8];
#pragma unroll
    for (int k = 0; k < 4; ++k) ob[k] = f2bf(s0[k] * acc[k] + t0[k] * R);
#pragma unroll
    for (int k = 0; k < 4; ++k) ob[4 + k] = f2bf(s1[k] * acc[4 + k] + t1[k] * R);
    *(short8*)(Aout + (size_t)b * NN * F + (size_t)dst * F + lane * 8) = *(short8*)ob;
}

// ---------------- bf16 MFMA GEMM (m97 structure): Y = lrelu(A @ W^T + bias) -> bf16 ----------------
// A [R,K] bf16, W [F,K] bf16, Y [R,F] bf16. R,F mult of 128, K mult of 32.
__global__ __launch_bounds__(256) void gemm_bias_lrelu(
    const unsigned short* __restrict__ A, const unsigned short* __restrict__ W,
    const float* __restrict__ bias, unsigned short* __restrict__ Y, int K, int F) {
    __shared__ unsigned short lds_a[128 * 32];
    __shared__ unsigned short lds_b[128 * 32];
    const int tid = threadIdx.x;
    const int row0 = blockIdx.x * 128;
    const int col0 = blockIdx.y * 128;
    const int wave = tid >> 6;
    const int lane = tid & 63;
    const int wr = (wave >> 1) * 64;
    const int wc = (wave & 1) * 64;
    const int lrow = lane & 15;
    const int q = lane >> 4;
    const int lr = lane >> 2;        // row within 16-row staging chunk
    const int lk = (lane & 3) * 8;   // ushort offset within 32-elem row

    f32x4 acc[4][4] = {};

    for (int k0 = 0; k0 < K; k0 += 32) {
#pragma unroll
        for (int t = 0; t < 2; ++t) {
            int r = wave * 32 + t * 16;
            gload16(A + (size_t)(row0 + r + lr) * K + k0 + lk, lds_a + r * 32);
            gload16(W + (size_t)(col0 + r + lr) * K + k0 + lk, lds_b + r * 32);
        }
        __syncthreads();
        short8 af[4], bf[4];
#pragma unroll
        for (int mt = 0; mt < 4; ++mt)
            af[mt] = *(const short8*)(lds_a + (wr + mt * 16 + lrow) * 32 + q * 8);
#pragma unroll
        for (int nt = 0; nt < 4; ++nt)
            bf[nt] = *(const short8*)(lds_b + (wc + nt * 16 + lrow) * 32 + q * 8);
#pragma unroll
        for (int mt = 0; mt < 4; ++mt)
#pragma unroll
            for (int nt = 0; nt < 4; ++nt)
                acc[mt][nt] = __builtin_amdgcn_mfma_f32_16x16x32_bf16(af[mt], bf[nt], acc[mt][nt], 0, 0, 0);
        __syncthreads();
    }
    // epilogue: C/D layout col=lane&15, row=q*4+reg
#pragma unroll
    for (int nt = 0; nt < 4; ++nt) {
        int col = col0 + wc + nt * 16 + lrow;
        float bv = bias[col];
#pragma unroll
        for (int mt = 0; mt < 4; ++mt) {
#pragma unroll
            for (int reg = 0; reg < 4; ++reg) {
                int row = row0 + wr + mt * 16 + q * 4 + reg;
                float v = acc[mt][nt][reg] + bv;
                v = (v > 0.f) ? v : 0.01f * v;
                Y[(size_t)row * F + col] = f2bf(v);
            }
        }
    }
}

// ---------------- batchnorm stats (reads bf16 Y) ----------------
__global__ __launch_bounds__(256) void bn_partial(const unsigned short* __restrict__ Y,
                                                  float* __restrict__ sum, float* __restrict__ sq, int F) {
    int c = blockIdx.x * 256 + threadIdx.x;
    int b = blockIdx.y;
    int n0 = blockIdx.z * 128;
    const unsigned short* p = Y + ((size_t)b * NN + n0) * F + c;
    float s = 0.f, s2 = 0.f;
#pragma unroll 4
    for (int i = 0; i < 128; ++i) {
        float v = bf2f(p[(size_t)i * F]);
        s += v;
        s2 += v * v;
    }
    atomicAdd(&sum[b * F + c], s);
    atomicAdd(&sq[b * F + c], s2);
}

__global__ void bn_finalize(const float* __restrict__ sum, const float* __restrict__ sq,
                            const float* __restrict__ g, const float* __restrict__ be,
                            float* __restrict__ s_arr, float* __restrict__ t_arr, int F) {
    int i = blockIdx.x * 256 + threadIdx.x;
    if (i >= BB * F) return;
    int c = i % F;
    float mu = sum[i] * (1.f / NN);
    float var = sq[i] * (1.f / NN) - mu * mu;
    float rs = rsqrtf(var + EPSF);
    float sc = g[c] * rs;
    s_arr[i] = sc;
    t_arr[i] = be[c] - mu * sc;
}

// ---------------- final layernorm (reads bf16 Y, applies layer-5 BN) ----------------
__global__ __launch_bounds__(256) void final_ln(const unsigned short* __restrict__ Y,
                                                const float* __restrict__ s_arr, const float* __restrict__ t_arr,
                                                const float* __restrict__ lng, const float* __restrict__ lnb,
                                                float* __restrict__ out) {
    int bn = blockIdx.x;
    int b = bn >> 11;
    int tid = threadIdx.x;
    u16x4 hr = ((const u16x4*)(Y + (size_t)bn * 1024))[tid];
    f32x4 h = {bf2f(hr[0]), bf2f(hr[1]), bf2f(hr[2]), bf2f(hr[3])};
    f32x4 sv = ((const f32x4*)(s_arr + b * 1024))[tid];
    f32x4 tv = ((const f32x4*)(t_arr + b * 1024))[tid];
    h = sv * h + tv;
    float s = h[0] + h[1] + h[2] + h[3];
    float s2 = h[0] * h[0] + h[1] * h[1] + h[2] * h[2] + h[3] * h[3];
#pragma unroll
    for (int off = 32; off; off >>= 1) {
        s += __shfl_down(s, off);
        s2 += __shfl_down(s2, off);
    }
    __shared__ float ssum[4], ssq[4];
    int wv = tid >> 6, ln = tid & 63;
    if (ln == 0) { ssum[wv] = s; ssq[wv] = s2; }
    __syncthreads();
    if (tid == 0) {
        float S = ssum[0] + ssum[1] + ssum[2] + ssum[3];
        float Q = ssq[0] + ssq[1] + ssq[2] + ssq[3];
        float mu = S * (1.f / 1024.f);
        float var = Q * (1.f / 1024.f) - mu * mu;
        ssum[0] = mu;
        ssq[0] = rsqrtf(var + EPSF);
    }
    __syncthreads();
    float mu = ssum[0], rs = ssq[0];
    f32x4 gv = ((const f32x4*)lng)[tid];
    f32x4 bv = ((const f32x4*)lnb)[tid];
    f32x4 o = (h - mu) * rs * gv + bv;
    ((f32x4*)(out + (size_t)bn * 1024))[tid] = o;
}

// ---------------- host ----------------
extern "C" void kernel_launch(void* const* d_in, const int* in_sizes, int n_in,
                              void* d_out, int out_size, void* d_ws, size_t ws_size,
                              hipStream_t stream) {
    const float* w[5]    = {(const float*)d_in[0], (const float*)d_in[4], (const float*)d_in[8],
                            (const float*)d_in[12], (const float*)d_in[16]};
    const float* bias[5] = {(const float*)d_in[1], (const float*)d_in[5], (const float*)d_in[9],
                            (const float*)d_in[13], (const float*)d_in[17]};
    const float* gam[5]  = {(const float*)d_in[2], (const float*)d_in[6], (const float*)d_in[10],
                            (const float*)d_in[14], (const float*)d_in[18]};
    const float* bet[5]  = {(const float*)d_in[3], (const float*)d_in[7], (const float*)d_in[11],
                            (const float*)d_in[15], (const float*)d_in[19]};
    const float* ln_g = (const float*)d_in[20];
    const float* ln_b = (const float*)d_in[21];
    const float* x    = (const float*)d_in[22];
    const int* ei     = (const int*)d_in[23];

    char* p = (char*)d_ws;
    auto alloc = [&](size_t bytes) {
        char* r = p;
        p += (bytes + 255) & ~(size_t)255;
        return r;
    };
    float* dinv    = (float*)alloc(NN * 4);
    float* rowsumR = (float*)alloc(NN * 4);
    int* row_ptr   = (int*)alloc((NN + 1) * 4);
    int* counts    = (int*)alloc(NN * 4);
    int* fillc     = (int*)alloc(NN * 4);
    int* colA      = (int*)alloc((size_t)(EE + NN) * 4);
    float* valA    = (float*)alloc((size_t)(EE + NN) * 4);
    float* bnsum   = (float*)alloc((size_t)BB * 1024 * 4);
    float* bnsq    = (float*)alloc((size_t)BB * 1024 * 4);
    float* s_arr   = (float*)alloc((size_t)BB * 1024 * 4);
    float* t_arr   = (float*)alloc((size_t)BB * 1024 * 4);
    const int wsz[5] = {256 * 64, 512 * 256, 1024 * 512, 1024 * 1024, 1024 * 1024};
    unsigned short* wbf[5];
    for (int i = 0; i < 5; ++i) wbf[i] = (unsigned short*)alloc((size_t)wsz[i] * 2);
    unsigned short* bufA = (unsigned short*)alloc((size_t)BB * NN * 1024 * 2);
    unsigned short* bufY = (unsigned short*)alloc((size_t)BB * NN * 1024 * 2);

    // graph build (once per call; CSR shared across batch & layers)
    zero_i32<<<(NN + 255) / 256, 256, 0, stream>>>(counts, NN);
    zero_i32<<<(NN + 255) / 256, 256, 0, stream>>>(fillc, NN);
    count_kernel<<<(EE + NN + 255) / 256, 256, 0, stream>>>(ei, counts);
    dinv_kernel<<<(NN + 255) / 256, 256, 0, stream>>>(counts, dinv);
    scan_kernel<<<1, 256, 0, stream>>>(counts, row_ptr);
    fill_kernel<<<(EE + NN + 255) / 256, 256, 0, stream>>>(ei, dinv, row_ptr, fillc, colA, valA);
    rowsum_kernel<<<(NN + 255) / 256, 256, 0, stream>>>(row_ptr, valA, rowsumR);

    for (int i = 0; i < 5; ++i)
        conv_bf16<<<(wsz[i] + 255) / 256, 256, 0, stream>>>(w[i], wbf[i], wsz[i]);

    const int Kin[5]  = {64, 256, 512, 1024, 1024};
    const int Fout[5] = {256, 512, 1024, 1024, 1024};
    for (int l = 0; l < 5; ++l) {
        int K = Kin[l], F = Fout[l];
        if (l == 0) {
            agg_f32<<<(NN / 16) * 8, 256, 0, stream>>>(x, row_ptr, colA, valA, bufA);
        } else {
            switch (K) {
                case 256:  // TPD=32, DPB=8
                    agg_bf16<32><<<(NN / 8) * 8, 256, 0, stream>>>(bufY, row_ptr, colA, valA, rowsumR, s_arr, t_arr, bufA, K);
                    break;
                case 512:  // TPD=64, DPB=4
                    agg_bf16<64><<<(NN / 4) * 8, 256, 0, stream>>>(bufY, row_ptr, colA, valA, rowsumR, s_arr, t_arr, bufA, K);
                    break;
                default:   // 1024: TPD=128, DPB=2
                    agg_bf16<128><<<(NN / 2) * 8, 256, 0, stream>>>(bufY, row_ptr, colA, valA, rowsumR, s_arr, t_arr, bufA, K);
                    break;
            }
        }
        gemm_bias_lrelu<<<dim3(BB * NN / 128, F / 128), 256, 0, stream>>>(bufA, wbf[l], bias[l], bufY, K, F);
        zero_f32<<<(BB * 1024 + 255) / 256, 256, 0, stream>>>(bnsum, BB * 1024);
        zero_f32<<<(BB * 1024 + 255) / 256, 256, 0, stream>>>(bnsq, BB * 1024);
        bn_partial<<<dim3(F / 256, BB, 16), 256, 0, stream>>>(bufY, bnsum, bnsq, F);
        bn_finalize<<<(BB * F + 255) / 256, 256, 0, stream>>>(bnsum, bnsq, gam[l], bet[l], s_arr, t_arr, F);
    }
    final_ln<<<BB * NN, 256, 0, stream>>>(bufY, s_arr, t_arr, ln_g, ln_b, (float*)d_out);
}

// Round 3
// 571.788 us; speedup vs baseline: 1.8896x; 1.2299x over previous
//
#include <hip/hip_runtime.h>

#define NN 2048
#define EE 65536
#define BB 8
#define EPSF 1e-5f

typedef __attribute__((ext_vector_type(4))) float f32x4;
typedef __attribute__((ext_vector_type(4))) int i32x4;
typedef __attribute__((ext_vector_type(8))) short short8;
typedef __attribute__((ext_vector_type(4))) unsigned short u16x4;

__device__ inline unsigned short f2bf(float f) {
    unsigned u = __float_as_uint(f);
    unsigned r = (u + 0x7fffu + ((u >> 16) & 1u)) >> 16;   // RNE
    return (unsigned short)r;
}
__device__ inline float bf2f(unsigned short u) {
    return __uint_as_float(((unsigned)u) << 16);
}

// async global->LDS, 16B per lane; lds dest = wave-uniform base + lane*16
__device__ inline void gload16(const unsigned short* g, unsigned short* l) {
    __builtin_amdgcn_global_load_lds(
        (const __attribute__((address_space(1))) void*)g,
        (__attribute__((address_space(3))) void*)l, 16, 0, 0);
}

// ---------------- graph build ----------------
__global__ void zero_i32(int* p, int n) {
    int i = blockIdx.x * 256 + threadIdx.x;
    if (i < n) p[i] = 0;
}
__global__ void zero_f32(float* p, int n) {
    int i = blockIdx.x * 256 + threadIdx.x;
    if (i < n) p[i] = 0.f;
}

__global__ void count_kernel(const int* __restrict__ ei, int* __restrict__ counts) {
    int e = blockIdx.x * 256 + threadIdx.x;
    if (e < EE + NN) {
        int d = (e < EE) ? ei[EE + e] : (e - EE);
        atomicAdd(&counts[d], 1);
    }
}

__global__ void dinv_kernel(const int* __restrict__ counts, float* __restrict__ dinv) {
    int i = blockIdx.x * 256 + threadIdx.x;
    if (i < NN) dinv[i] = rsqrtf((float)counts[i]);
}

// exclusive scan of counts PADDED UP TO MULTIPLE OF 4 -> row_ptr (aligned CSR rows)
__global__ void scan_kernel(const int* __restrict__ counts, int* __restrict__ row_ptr) {
    __shared__ int sh[256];
    int tid = threadIdx.x;
    int loc[8];
    int run = 0;
#pragma unroll
    for (int i = 0; i < 8; ++i) {
        loc[i] = run;
        run += (counts[tid * 8 + i] + 3) & ~3;
    }
    sh[tid] = run;
    __syncthreads();
    for (int off = 1; off < 256; off <<= 1) {
        int v = (tid >= off) ? sh[tid - off] : 0;
        __syncthreads();
        sh[tid] += v;
        __syncthreads();
    }
    int excl = sh[tid] - run;
#pragma unroll
    for (int i = 0; i < 8; ++i) row_ptr[tid * 8 + i] = excl + loc[i];
    if (tid == 255) row_ptr[NN] = excl + run;
}

__global__ void fill_kernel(const int* __restrict__ ei, const float* __restrict__ dinv,
                            const int* __restrict__ row_ptr, int* __restrict__ fillc,
                            int* __restrict__ colA, float* __restrict__ valA) {
    int e = blockIdx.x * 256 + threadIdx.x;
    if (e < EE + NN) {
        int s, d;
        if (e < EE) { s = ei[e]; d = ei[EE + e]; }
        else        { s = d = e - EE; }
        int pos = row_ptr[d] + atomicAdd(&fillc[d], 1);
        colA[pos] = s;
        valA[pos] = dinv[s] * dinv[d];
    }
}

// fill pad slots (col=dst, val=0) so every row is a multiple of 4 edges
__global__ void pad_kernel(const int* __restrict__ counts, const int* __restrict__ row_ptr,
                           int* __restrict__ colA, float* __restrict__ valA) {
    int d = blockIdx.x * 256 + threadIdx.x;
    if (d < NN) {
        int beg = row_ptr[d], end = row_ptr[d + 1];
        for (int k = counts[d]; k < end - beg; ++k) {
            colA[beg + k] = d;
            valA[beg + k] = 0.f;
        }
    }
}

__global__ void rowsum_kernel(const int* __restrict__ row_ptr, const float* __restrict__ valA,
                              float* __restrict__ R) {
    int d = blockIdx.x * 256 + threadIdx.x;
    if (d < NN) {
        float s = 0.f;
        for (int j = row_ptr[d]; j < row_ptr[d + 1]; ++j) s += valA[j];
        R[d] = s;
    }
}

__global__ void conv_bf16(const float* __restrict__ src, unsigned short* __restrict__ dst, int n) {
    int i = blockIdx.x * 256 + threadIdx.x;
    if (i < n) dst[i] = f2bf(src[i]);
}

// ---------------- aggregation, layer 1 (f32 input x, F=64) ----------------
__global__ __launch_bounds__(256) void agg_f32(
    const float* __restrict__ Yin, const int* __restrict__ row_ptr,
    const int* __restrict__ colA, const float* __restrict__ valA,
    unsigned short* __restrict__ Aout) {
    constexpr int TPD = 16, DPB = 16, F = 64;
    int b = blockIdx.x & 7;
    int dst = (blockIdx.x >> 3) * DPB + threadIdx.x / TPD;
    int lane = threadIdx.x % TPD;
    const f32x4* Yb = (const f32x4*)(Yin + (size_t)b * NN * F);
    int beg = row_ptr[dst], end = row_ptr[dst + 1];
    f32x4 acc = {0.f, 0.f, 0.f, 0.f};
    for (int j = beg; j < end; j += 4) {
        i32x4 c4 = *(const i32x4*)(colA + j);
        f32x4 v4 = *(const f32x4*)(valA + j);
        f32x4 y0 = Yb[(size_t)c4[0] * (F / 4) + lane];
        f32x4 y1 = Yb[(size_t)c4[1] * (F / 4) + lane];
        f32x4 y2 = Yb[(size_t)c4[2] * (F / 4) + lane];
        f32x4 y3 = Yb[(size_t)c4[3] * (F / 4) + lane];
        acc += v4[0] * y0;
        acc += v4[1] * y1;
        acc += v4[2] * y2;
        acc += v4[3] * y3;
    }
    u16x4 ob = {f2bf(acc[0]), f2bf(acc[1]), f2bf(acc[2]), f2bf(acc[3])};
    *(u16x4*)(Aout + (size_t)b * NN * F + (size_t)dst * F + lane * 4) = ob;
}

// ---------------- aggregation, layers 2..5 (bf16 Y, BN affine folded) ----------------
// Aout[b][dst][f] = s[b][f] * sum_j val[j]*Y[b][col[j]][f] + t[b][f]*R[dst]
template <int TPD>
__global__ __launch_bounds__(256) void agg_bf16(
    const unsigned short* __restrict__ Yin, const int* __restrict__ row_ptr,
    const int* __restrict__ colA, const float* __restrict__ valA,
    const float* __restrict__ rowsumR, const float* __restrict__ s_arr,
    const float* __restrict__ t_arr, unsigned short* __restrict__ Aout, int F) {
    constexpr int DPB = 256 / TPD;
    int b = blockIdx.x & 7;
    int dst = (blockIdx.x >> 3) * DPB + threadIdx.x / TPD;
    int lane = threadIdx.x % TPD;
    const unsigned short* Yb = Yin + (size_t)b * NN * F;
    int beg = row_ptr[dst], end = row_ptr[dst + 1];
    float acc[8] = {};
    for (int j = beg; j < end; j += 4) {
        i32x4 c4 = *(const i32x4*)(colA + j);
        f32x4 v4 = *(const f32x4*)(valA + j);
        short8 y0 = *(const short8*)(Yb + (size_t)c4[0] * F + lane * 8);
        short8 y1 = *(const short8*)(Yb + (size_t)c4[1] * F + lane * 8);
        short8 y2 = *(const short8*)(Yb + (size_t)c4[2] * F + lane * 8);
        short8 y3 = *(const short8*)(Yb + (size_t)c4[3] * F + lane * 8);
#pragma unroll
        for (int k = 0; k < 8; ++k) {
            acc[k] += v4[0] * bf2f((unsigned short)y0[k]);
            acc[k] += v4[1] * bf2f((unsigned short)y1[k]);
            acc[k] += v4[2] * bf2f((unsigned short)y2[k]);
            acc[k] += v4[3] * bf2f((unsigned short)y3[k]);
        }
    }
    float R = rowsumR[dst];
    f32x4 s0 = ((const f32x4*)(s_arr + b * F))[lane * 2];
    f32x4 s1 = ((const f32x4*)(s_arr + b * F))[lane * 2 + 1];
    f32x4 t0 = ((const f32x4*)(t_arr + b * F))[lane * 2];
    f32x4 t1 = ((const f32x4*)(t_arr + b * F))[lane * 2 + 1];
    unsigned short ob[8];
#pragma unroll
    for (int k = 0; k < 4; ++k) ob[k] = f2bf(s0[k] * acc[k] + t0[k] * R);
#pragma unroll
    for (int k = 0; k < 4; ++k) ob[4 + k] = f2bf(s1[k] * acc[4 + k] + t1[k] * R);
    *(short8*)(Aout + (size_t)b * NN * F + (size_t)dst * F + lane * 8) = *(short8*)ob;
}

// ---------------- bf16 MFMA GEMM: Y = lrelu(A @ W^T + bias) -> bf16, BN stats fused ----------------
// A [R,K] bf16, W [F,K] bf16, Y [R,F] bf16. R,F mult of 128, K mult of 32.
__global__ __launch_bounds__(256) void gemm_bias_lrelu(
    const unsigned short* __restrict__ A, const unsigned short* __restrict__ W,
    const float* __restrict__ bias, unsigned short* __restrict__ Y,
    float* __restrict__ bnsum, float* __restrict__ bnsq, int K, int F) {
    __shared__ unsigned short lds_a[128 * 32];
    __shared__ unsigned short lds_b[128 * 32];
    const int tid = threadIdx.x;
    const int row0 = blockIdx.x * 128;
    const int col0 = blockIdx.y * 128;
    const int b = row0 >> 11;  // 2048 rows per graph
    const int wave = tid >> 6;
    const int lane = tid & 63;
    const int wr = (wave >> 1) * 64;
    const int wc = (wave & 1) * 64;
    const int lrow = lane & 15;
    const int q = lane >> 4;
    const int lr = lane >> 2;
    const int lk = (lane & 3) * 8;

    f32x4 acc[4][4] = {};

    for (int k0 = 0; k0 < K; k0 += 32) {
#pragma unroll
        for (int t = 0; t < 2; ++t) {
            int r = wave * 32 + t * 16;
            gload16(A + (size_t)(row0 + r + lr) * K + k0 + lk, lds_a + r * 32);
            gload16(W + (size_t)(col0 + r + lr) * K + k0 + lk, lds_b + r * 32);
        }
        __syncthreads();
        short8 af[4], bf[4];
#pragma unroll
        for (int mt = 0; mt < 4; ++mt)
            af[mt] = *(const short8*)(lds_a + (wr + mt * 16 + lrow) * 32 + q * 8);
#pragma unroll
        for (int nt = 0; nt < 4; ++nt)
            bf[nt] = *(const short8*)(lds_b + (wc + nt * 16 + lrow) * 32 + q * 8);
#pragma unroll
        for (int mt = 0; mt < 4; ++mt)
#pragma unroll
            for (int nt = 0; nt < 4; ++nt)
                acc[mt][nt] = __builtin_amdgcn_mfma_f32_16x16x32_bf16(af[mt], bf[nt], acc[mt][nt], 0, 0, 0);
        __syncthreads();
    }
    // epilogue: C/D layout col=lane&15, row=q*4+reg; fused BN-stat accumulation
#pragma unroll
    for (int nt = 0; nt < 4; ++nt) {
        int col = col0 + wc + nt * 16 + lrow;
        float bv = bias[col];
        float s = 0.f, s2 = 0.f;
#pragma unroll
        for (int mt = 0; mt < 4; ++mt) {
#pragma unroll
            for (int reg = 0; reg < 4; ++reg) {
                int row = row0 + wr + mt * 16 + q * 4 + reg;
                float v = acc[mt][nt][reg] + bv;
                v = (v > 0.f) ? v : 0.01f * v;
                s += v;
                s2 += v * v;
                Y[(size_t)row * F + col] = f2bf(v);
            }
        }
        s += __shfl_xor(s, 16);
        s2 += __shfl_xor(s2, 16);
        s += __shfl_xor(s, 32);
        s2 += __shfl_xor(s2, 32);
        if (q == 0) {
            atomicAdd(&bnsum[b * F + col], s);
            atomicAdd(&bnsq[b * F + col], s2);
        }
    }
}

__global__ void bn_finalize(const float* __restrict__ sum, const float* __restrict__ sq,
                            const float* __restrict__ g, const float* __restrict__ be,
                            float* __restrict__ s_arr, float* __restrict__ t_arr, int F) {
    int i = blockIdx.x * 256 + threadIdx.x;
    if (i >= BB * F) return;
    int c = i % F;
    float mu = sum[i] * (1.f / NN);
    float var = sq[i] * (1.f / NN) - mu * mu;
    float rs = rsqrtf(var + EPSF);
    float sc = g[c] * rs;
    s_arr[i] = sc;
    t_arr[i] = be[c] - mu * sc;
}

// ---------------- final layernorm (reads bf16 Y, applies layer-5 BN) ----------------
__global__ __launch_bounds__(256) void final_ln(const unsigned short* __restrict__ Y,
                                                const float* __restrict__ s_arr, const float* __restrict__ t_arr,
                                                const float* __restrict__ lng, const float* __restrict__ lnb,
                                                float* __restrict__ out) {
    int bn = blockIdx.x;
    int b = bn >> 11;
    int tid = threadIdx.x;
    u16x4 hr = ((const u16x4*)(Y + (size_t)bn * 1024))[tid];
    f32x4 h = {bf2f(hr[0]), bf2f(hr[1]), bf2f(hr[2]), bf2f(hr[3])};
    f32x4 sv = ((const f32x4*)(s_arr + b * 1024))[tid];
    f32x4 tv = ((const f32x4*)(t_arr + b * 1024))[tid];
    h = sv * h + tv;
    float s = h[0] + h[1] + h[2] + h[3];
    float s2 = h[0] * h[0] + h[1] * h[1] + h[2] * h[2] + h[3] * h[3];
#pragma unroll
    for (int off = 32; off; off >>= 1) {
        s += __shfl_down(s, off);
        s2 += __shfl_down(s2, off);
    }
    __shared__ float ssum[4], ssq[4];
    int wv = tid >> 6, ln = tid & 63;
    if (ln == 0) { ssum[wv] = s; ssq[wv] = s2; }
    __syncthreads();
    if (tid == 0) {
        float S = ssum[0] + ssum[1] + ssum[2] + ssum[3];
        float Q = ssq[0] + ssq[1] + ssq[2] + ssq[3];
        float mu = S * (1.f / 1024.f);
        float var = Q * (1.f / 1024.f) - mu * mu;
        ssum[0] = mu;
        ssq[0] = rsqrtf(var + EPSF);
    }
    __syncthreads();
    float mu = ssum[0], rs = ssq[0];
    f32x4 gv = ((const f32x4*)lng)[tid];
    f32x4 bv = ((const f32x4*)lnb)[tid];
    f32x4 o = (h - mu) * rs * gv + bv;
    ((f32x4*)(out + (size_t)bn * 1024))[tid] = o;
}

// ---------------- host ----------------
extern "C" void kernel_launch(void* const* d_in, const int* in_sizes, int n_in,
                              void* d_out, int out_size, void* d_ws, size_t ws_size,
                              hipStream_t stream) {
    const float* w[5]    = {(const float*)d_in[0], (const float*)d_in[4], (const float*)d_in[8],
                            (const float*)d_in[12], (const float*)d_in[16]};
    const float* bias[5] = {(const float*)d_in[1], (const float*)d_in[5], (const float*)d_in[9],
                            (const float*)d_in[13], (const float*)d_in[17]};
    const float* gam[5]  = {(const float*)d_in[2], (const float*)d_in[6], (const float*)d_in[10],
                            (const float*)d_in[14], (const float*)d_in[18]};
    const float* bet[5]  = {(const float*)d_in[3], (const float*)d_in[7], (const float*)d_in[11],
                            (const float*)d_in[15], (const float*)d_in[19]};
    const float* ln_g = (const float*)d_in[20];
    const float* ln_b = (const float*)d_in[21];
    const float* x    = (const float*)d_in[22];
    const int* ei     = (const int*)d_in[23];

    char* p = (char*)d_ws;
    auto alloc = [&](size_t bytes) {
        char* r = p;
        p += (bytes + 255) & ~(size_t)255;
        return r;
    };
    const int MAXE = EE + 4 * NN;  // padded CSR capacity
    float* dinv    = (float*)alloc(NN * 4);
    float* rowsumR = (float*)alloc(NN * 4);
    int* row_ptr   = (int*)alloc((NN + 1) * 4);
    int* counts    = (int*)alloc(NN * 4);
    int* fillc     = (int*)alloc(NN * 4);
    int* colA      = (int*)alloc((size_t)MAXE * 4);
    float* valA    = (float*)alloc((size_t)MAXE * 4);
    float* bnsum   = (float*)alloc((size_t)5 * BB * 1024 * 4);
    float* bnsq    = (float*)alloc((size_t)5 * BB * 1024 * 4);
    float* s_arr   = (float*)alloc((size_t)BB * 1024 * 4);
    float* t_arr   = (float*)alloc((size_t)BB * 1024 * 4);
    const int wsz[5] = {256 * 64, 512 * 256, 1024 * 512, 1024 * 1024, 1024 * 1024};
    unsigned short* wbf[5];
    for (int i = 0; i < 5; ++i) wbf[i] = (unsigned short*)alloc((size_t)wsz[i] * 2);
    unsigned short* bufA = (unsigned short*)alloc((size_t)BB * NN * 1024 * 2);
    unsigned short* bufY = (unsigned short*)alloc((size_t)BB * NN * 1024 * 2);

    // graph build (once per call; padded CSR shared across batch & layers)
    zero_i32<<<(NN + 255) / 256, 256, 0, stream>>>(counts, NN);
    zero_i32<<<(NN + 255) / 256, 256, 0, stream>>>(fillc, NN);
    zero_f32<<<(5 * BB * 1024 + 255) / 256, 256, 0, stream>>>(bnsum, 5 * BB * 1024);
    zero_f32<<<(5 * BB * 1024 + 255) / 256, 256, 0, stream>>>(bnsq, 5 * BB * 1024);
    count_kernel<<<(EE + NN + 255) / 256, 256, 0, stream>>>(ei, counts);
    dinv_kernel<<<(NN + 255) / 256, 256, 0, stream>>>(counts, dinv);
    scan_kernel<<<1, 256, 0, stream>>>(counts, row_ptr);
    fill_kernel<<<(EE + NN + 255) / 256, 256, 0, stream>>>(ei, dinv, row_ptr, fillc, colA, valA);
    pad_kernel<<<(NN + 255) / 256, 256, 0, stream>>>(counts, row_ptr, colA, valA);
    rowsum_kernel<<<(NN + 255) / 256, 256, 0, stream>>>(row_ptr, valA, rowsumR);

    for (int i = 0; i < 5; ++i)
        conv_bf16<<<(wsz[i] + 255) / 256, 256, 0, stream>>>(w[i], wbf[i], wsz[i]);

    const int Kin[5]  = {64, 256, 512, 1024, 1024};
    const int Fout[5] = {256, 512, 1024, 1024, 1024};
    for (int l = 0; l < 5; ++l) {
        int K = Kin[l], F = Fout[l];
        if (l == 0) {
            agg_f32<<<(NN / 16) * 8, 256, 0, stream>>>(x, row_ptr, colA, valA, bufA);
        } else {
            switch (K) {
                case 256:
                    agg_bf16<32><<<(NN / 8) * 8, 256, 0, stream>>>(bufY, row_ptr, colA, valA, rowsumR, s_arr, t_arr, bufA, K);
                    break;
                case 512:
                    agg_bf16<64><<<(NN / 4) * 8, 256, 0, stream>>>(bufY, row_ptr, colA, valA, rowsumR, s_arr, t_arr, bufA, K);
                    break;
                default:
                    agg_bf16<128><<<(NN / 2) * 8, 256, 0, stream>>>(bufY, row_ptr, colA, valA, rowsumR, s_arr, t_arr, bufA, K);
                    break;
            }
        }
        gemm_bias_lrelu<<<dim3(BB * NN / 128, F / 128), 256, 0, stream>>>(
            bufA, wbf[l], bias[l], bufY, bnsum + l * BB * 1024, bnsq + l * BB * 1024, K, F);
        bn_finalize<<<(BB * F + 255) / 256, 256, 0, stream>>>(
            bnsum + l * BB * 1024, bnsq + l * BB * 1024, gam[l], bet[l], s_arr, t_arr, F);
    }
    final_ln<<<BB * NN, 256, 0, stream>>>(bufY, s_arr, t_arr, ln_g, ln_b, (float*)d_out);
}

// Round 4
// 551.729 us; speedup vs baseline: 1.9583x; 1.0364x over previous
//
#include <hip/hip_runtime.h>

#define NN 2048
#define EE 65536
#define BB 8
#define EPSF 1e-5f

typedef __attribute__((ext_vector_type(2))) float f32x2;
typedef __attribute__((ext_vector_type(4))) float f32x4;
typedef __attribute__((ext_vector_type(4))) int i32x4;
typedef __attribute__((ext_vector_type(4))) unsigned int u32x4;
typedef __attribute__((ext_vector_type(8))) short short8;
typedef __attribute__((ext_vector_type(4))) unsigned short u16x4;

__device__ inline unsigned short f2bf(float f) {
    unsigned u = __float_as_uint(f);
    unsigned r = (u + 0x7fffu + ((u >> 16) & 1u)) >> 16;   // RNE
    return (unsigned short)r;
}
__device__ inline float bf2f(unsigned short u) {
    return __uint_as_float(((unsigned)u) << 16);
}

// async global->LDS, 16B per lane; lds dest = wave-uniform base + lane*16
__device__ inline void gload16(const unsigned short* g, unsigned short* l) {
    __builtin_amdgcn_global_load_lds(
        (const __attribute__((address_space(1))) void*)g,
        (__attribute__((address_space(3))) void*)l, 16, 0, 0);
}

// ---------------- graph build ----------------
__global__ void setup_zero(int* __restrict__ counts, int* __restrict__ fillc,
                           float* __restrict__ bnsum, float* __restrict__ bnsq) {
    int i = blockIdx.x * 256 + threadIdx.x;
    if (i < NN) { counts[i] = 0; fillc[i] = 0; }
    if (i < 5 * BB * 1024) { bnsum[i] = 0.f; bnsq[i] = 0.f; }
}

__global__ void count_kernel(const int* __restrict__ ei, int* __restrict__ counts) {
    int e = blockIdx.x * 256 + threadIdx.x;
    if (e < EE + NN) {
        int d = (e < EE) ? ei[EE + e] : (e - EE);
        atomicAdd(&counts[d], 1);
    }
}

__global__ void dinv_kernel(const int* __restrict__ counts, float* __restrict__ dinv) {
    int i = blockIdx.x * 256 + threadIdx.x;
    if (i < NN) dinv[i] = rsqrtf((float)counts[i]);
}

// exclusive scan of counts PADDED UP TO MULTIPLE OF 8 -> row_ptr (aligned CSR rows)
__global__ void scan_kernel(const int* __restrict__ counts, int* __restrict__ row_ptr) {
    __shared__ int sh[256];
    int tid = threadIdx.x;
    int loc[8];
    int run = 0;
#pragma unroll
    for (int i = 0; i < 8; ++i) {
        loc[i] = run;
        run += (counts[tid * 8 + i] + 7) & ~7;
    }
    sh[tid] = run;
    __syncthreads();
    for (int off = 1; off < 256; off <<= 1) {
        int v = (tid >= off) ? sh[tid - off] : 0;
        __syncthreads();
        sh[tid] += v;
        __syncthreads();
    }
    int excl = sh[tid] - run;
#pragma unroll
    for (int i = 0; i < 8; ++i) row_ptr[tid * 8 + i] = excl + loc[i];
    if (tid == 255) row_ptr[NN] = excl + run;
}

// fill real edges (atomic slot) + fill pad slots (col=dst, val=0); disjoint ranges
__global__ void fill_pad(const int* __restrict__ ei, const float* __restrict__ dinv,
                         const int* __restrict__ row_ptr, const int* __restrict__ counts,
                         int* __restrict__ fillc, int* __restrict__ colA, float* __restrict__ valA) {
    int e = blockIdx.x * 256 + threadIdx.x;
    if (e < EE + NN) {
        int s, d;
        if (e < EE) { s = ei[e]; d = ei[EE + e]; }
        else        { s = d = e - EE; }
        int pos = row_ptr[d] + atomicAdd(&fillc[d], 1);
        colA[pos] = s;
        valA[pos] = dinv[s] * dinv[d];
    } else if (e < EE + 2 * NN) {
        int d = e - (EE + NN);
        int beg = row_ptr[d], end = row_ptr[d + 1];
        for (int k = counts[d]; k < end - beg; ++k) {
            colA[beg + k] = d;
            valA[beg + k] = 0.f;
        }
    }
}

__global__ void rowsum_kernel(const int* __restrict__ row_ptr, const float* __restrict__ valA,
                              float* __restrict__ R) {
    int d = blockIdx.x * 256 + threadIdx.x;
    if (d < NN) {
        float s = 0.f;
        for (int j = row_ptr[d]; j < row_ptr[d + 1]; ++j) s += valA[j];
        R[d] = s;
    }
}

// all 5 weight matrices -> one contiguous bf16 buffer
#define WO1 16384
#define WO2 (WO1 + 131072)
#define WO3 (WO2 + 524288)
#define WO4 (WO3 + 1048576)
#define WO5 (WO4 + 1048576)
__global__ void conv_all(const float* __restrict__ s0, const float* __restrict__ s1,
                         const float* __restrict__ s2, const float* __restrict__ s3,
                         const float* __restrict__ s4, unsigned short* __restrict__ dst) {
    int i = blockIdx.x * 256 + threadIdx.x;
    if (i >= WO5) return;
    float v;
    if (i < WO1)      v = s0[i];
    else if (i < WO2) v = s1[i - WO1];
    else if (i < WO3) v = s2[i - WO2];
    else if (i < WO4) v = s3[i - WO3];
    else              v = s4[i - WO4];
    dst[i] = f2bf(v);
}

// ---------------- aggregation, layer 1 (f32 input x, F=64) ----------------
__global__ __launch_bounds__(256) void agg_f32(
    const float* __restrict__ Yin, const int* __restrict__ row_ptr,
    const int* __restrict__ colA, const float* __restrict__ valA,
    unsigned short* __restrict__ Aout) {
    constexpr int TPD = 16, DPB = 16, F = 64;
    int b = blockIdx.x & 7;
    int dst = (blockIdx.x >> 3) * DPB + threadIdx.x / TPD;
    int lane = threadIdx.x % TPD;
    const f32x4* Yb = (const f32x4*)(Yin + (size_t)b * NN * F);
    int beg = row_ptr[dst], end = row_ptr[dst + 1];
    f32x4 acc = {0.f, 0.f, 0.f, 0.f};
    for (int j = beg; j < end; j += 8) {
        i32x4 ca = *(const i32x4*)(colA + j);
        i32x4 cb = *(const i32x4*)(colA + j + 4);
        f32x4 va = *(const f32x4*)(valA + j);
        f32x4 vb = *(const f32x4*)(valA + j + 4);
        f32x4 y[8];
#pragma unroll
        for (int e = 0; e < 4; ++e) y[e] = Yb[(size_t)ca[e] * (F / 4) + lane];
#pragma unroll
        for (int e = 0; e < 4; ++e) y[4 + e] = Yb[(size_t)cb[e] * (F / 4) + lane];
#pragma unroll
        for (int e = 0; e < 8; ++e) {
            float ve = (e < 4) ? va[e] : vb[e - 4];
            acc += ve * y[e];
        }
    }
    u16x4 ob = {f2bf(acc[0]), f2bf(acc[1]), f2bf(acc[2]), f2bf(acc[3])};
    *(u16x4*)(Aout + (size_t)b * NN * F + (size_t)dst * F + lane * 4) = ob;
}

// ---------------- aggregation, layers 2..5 (bf16 Y, BN affine folded) ----------------
// Aout[b][dst][f] = s[b][f] * sum_j val[j]*Y[b][col[j]][f] + t[b][f]*R[dst]
// F/8 threads per dst, 8 bf16 feats (4 dwords) per thread; feature pairs kept packed:
// lo = w<<16, hi = w&0xffff0000, float2 acc -> v_pk_fma_f32.
template <int F>
__global__ __launch_bounds__(256) void agg_bf16(
    const unsigned short* __restrict__ Yin, const int* __restrict__ row_ptr,
    const int* __restrict__ colA, const float* __restrict__ valA,
    const float* __restrict__ rowsumR, const float* __restrict__ s_arr,
    const float* __restrict__ t_arr, unsigned short* __restrict__ Aout) {
    constexpr int TPD = F / 8;
    constexpr int DPB = 256 / TPD;
    int b = blockIdx.x & 7;
    int dst = (blockIdx.x >> 3) * DPB + threadIdx.x / TPD;
    int lane = threadIdx.x % TPD;
    const u32x4* Yb4 = (const u32x4*)(Yin + (size_t)b * NN * F);
    int beg = row_ptr[dst], end = row_ptr[dst + 1];
    f32x2 acc[4] = {};
    for (int j = beg; j < end; j += 8) {
        i32x4 ca = *(const i32x4*)(colA + j);
        i32x4 cb = *(const i32x4*)(colA + j + 4);
        f32x4 va = *(const f32x4*)(valA + j);
        f32x4 vb = *(const f32x4*)(valA + j + 4);
        u32x4 y[8];
#pragma unroll
        for (int e = 0; e < 4; ++e) y[e] = Yb4[(size_t)ca[e] * (F / 8) + lane];
#pragma unroll
        for (int e = 0; e < 4; ++e) y[4 + e] = Yb4[(size_t)cb[e] * (F / 8) + lane];
#pragma unroll
        for (int e = 0; e < 8; ++e) {
            float ve = (e < 4) ? va[e] : vb[e - 4];
            f32x2 vv = {ve, ve};
#pragma unroll
            for (int d = 0; d < 4; ++d) {
                unsigned w = y[e][d];
                f32x2 f = {__uint_as_float(w << 16), __uint_as_float(w & 0xffff0000u)};
                acc[d] += vv * f;
            }
        }
    }
    float R = rowsumR[dst];
    const float* sb = s_arr + b * F + lane * 8;
    const float* tb = t_arr + b * F + lane * 8;
    unsigned short ob[8];
#pragma unroll
    for (int k = 0; k < 8; ++k)
        ob[k] = f2bf(sb[k] * acc[k >> 1][k & 1] + tb[k] * R);
    *(short8*)(Aout + (size_t)b * NN * F + (size_t)dst * F + lane * 8) = *(short8*)ob;
}

// ---------------- bf16 MFMA GEMM: Y = lrelu(A @ W^T + bias) -> bf16, BN stats fused ----------------
__global__ __launch_bounds__(256) void gemm_bias_lrelu(
    const unsigned short* __restrict__ A, const unsigned short* __restrict__ W,
    const float* __restrict__ bias, unsigned short* __restrict__ Y,
    float* __restrict__ bnsum, float* __restrict__ bnsq, int K, int F) {
    __shared__ unsigned short lds_a[128 * 32];
    __shared__ unsigned short lds_b[128 * 32];
    const int tid = threadIdx.x;
    const int row0 = blockIdx.x * 128;
    const int col0 = blockIdx.y * 128;
    const int b = row0 >> 11;
    const int wave = tid >> 6;
    const int lane = tid & 63;
    const int wr = (wave >> 1) * 64;
    const int wc = (wave & 1) * 64;
    const int lrow = lane & 15;
    const int q = lane >> 4;
    const int lr = lane >> 2;
    const int lk = (lane & 3) * 8;

    f32x4 acc[4][4] = {};

    for (int k0 = 0; k0 < K; k0 += 32) {
#pragma unroll
        for (int t = 0; t < 2; ++t) {
            int r = wave * 32 + t * 16;
            gload16(A + (size_t)(row0 + r + lr) * K + k0 + lk, lds_a + r * 32);
            gload16(W + (size_t)(col0 + r + lr) * K + k0 + lk, lds_b + r * 32);
        }
        __syncthreads();
        short8 af[4], bf[4];
#pragma unroll
        for (int mt = 0; mt < 4; ++mt)
            af[mt] = *(const short8*)(lds_a + (wr + mt * 16 + lrow) * 32 + q * 8);
#pragma unroll
        for (int nt = 0; nt < 4; ++nt)
            bf[nt] = *(const short8*)(lds_b + (wc + nt * 16 + lrow) * 32 + q * 8);
#pragma unroll
        for (int mt = 0; mt < 4; ++mt)
#pragma unroll
            for (int nt = 0; nt < 4; ++nt)
                acc[mt][nt] = __builtin_amdgcn_mfma_f32_16x16x32_bf16(af[mt], bf[nt], acc[mt][nt], 0, 0, 0);
        __syncthreads();
    }
#pragma unroll
    for (int nt = 0; nt < 4; ++nt) {
        int col = col0 + wc + nt * 16 + lrow;
        float bv = bias[col];
        float s = 0.f, s2 = 0.f;
#pragma unroll
        for (int mt = 0; mt < 4; ++mt) {
#pragma unroll
            for (int reg = 0; reg < 4; ++reg) {
                int row = row0 + wr + mt * 16 + q * 4 + reg;
                float v = acc[mt][nt][reg] + bv;
                v = (v > 0.f) ? v : 0.01f * v;
                s += v;
                s2 += v * v;
                Y[(size_t)row * F + col] = f2bf(v);
            }
        }
        s += __shfl_xor(s, 16);
        s2 += __shfl_xor(s2, 16);
        s += __shfl_xor(s, 32);
        s2 += __shfl_xor(s2, 32);
        if (q == 0) {
            atomicAdd(&bnsum[b * F + col], s);
            atomicAdd(&bnsq[b * F + col], s2);
        }
    }
}

__global__ void bn_finalize(const float* __restrict__ sum, const float* __restrict__ sq,
                            const float* __restrict__ g, const float* __restrict__ be,
                            float* __restrict__ s_arr, float* __restrict__ t_arr, int F) {
    int i = blockIdx.x * 256 + threadIdx.x;
    if (i >= BB * F) return;
    int c = i % F;
    float mu = sum[i] * (1.f / NN);
    float var = sq[i] * (1.f / NN) - mu * mu;
    float rs = rsqrtf(var + EPSF);
    float sc = g[c] * rs;
    s_arr[i] = sc;
    t_arr[i] = be[c] - mu * sc;
}

// ---------------- final layernorm (reads bf16 Y, applies layer-5 BN) ----------------
__global__ __launch_bounds__(256) void final_ln(const unsigned short* __restrict__ Y,
                                                const float* __restrict__ s_arr, const float* __restrict__ t_arr,
                                                const float* __restrict__ lng, const float* __restrict__ lnb,
                                                float* __restrict__ out) {
    int bn = blockIdx.x;
    int b = bn >> 11;
    int tid = threadIdx.x;
    u16x4 hr = ((const u16x4*)(Y + (size_t)bn * 1024))[tid];
    f32x4 h = {bf2f(hr[0]), bf2f(hr[1]), bf2f(hr[2]), bf2f(hr[3])};
    f32x4 sv = ((const f32x4*)(s_arr + b * 1024))[tid];
    f32x4 tv = ((const f32x4*)(t_arr + b * 1024))[tid];
    h = sv * h + tv;
    float s = h[0] + h[1] + h[2] + h[3];
    float s2 = h[0] * h[0] + h[1] * h[1] + h[2] * h[2] + h[3] * h[3];
#pragma unroll
    for (int off = 32; off; off >>= 1) {
        s += __shfl_down(s, off);
        s2 += __shfl_down(s2, off);
    }
    __shared__ float ssum[4], ssq[4];
    int wv = tid >> 6, ln = tid & 63;
    if (ln == 0) { ssum[wv] = s; ssq[wv] = s2; }
    __syncthreads();
    if (tid == 0) {
        float S = ssum[0] + ssum[1] + ssum[2] + ssum[3];
        float Q = ssq[0] + ssq[1] + ssq[2] + ssq[3];
        float mu = S * (1.f / 1024.f);
        float var = Q * (1.f / 1024.f) - mu * mu;
        ssum[0] = mu;
        ssq[0] = rsqrtf(var + EPSF);
    }
    __syncthreads();
    float mu = ssum[0], rs = ssq[0];
    f32x4 gv = ((const f32x4*)lng)[tid];
    f32x4 bv = ((const f32x4*)lnb)[tid];
    f32x4 o = (h - mu) * rs * gv + bv;
    ((f32x4*)(out + (size_t)bn * 1024))[tid] = o;
}

// ---------------- host ----------------
extern "C" void kernel_launch(void* const* d_in, const int* in_sizes, int n_in,
                              void* d_out, int out_size, void* d_ws, size_t ws_size,
                              hipStream_t stream) {
    const float* w[5]    = {(const float*)d_in[0], (const float*)d_in[4], (const float*)d_in[8],
                            (const float*)d_in[12], (const float*)d_in[16]};
    const float* bias[5] = {(const float*)d_in[1], (const float*)d_in[5], (const float*)d_in[9],
                            (const float*)d_in[13], (const float*)d_in[17]};
    const float* gam[5]  = {(const float*)d_in[2], (const float*)d_in[6], (const float*)d_in[10],
                            (const float*)d_in[14], (const float*)d_in[18]};
    const float* bet[5]  = {(const float*)d_in[3], (const float*)d_in[7], (const float*)d_in[11],
                            (const float*)d_in[15], (const float*)d_in[19]};
    const float* ln_g = (const float*)d_in[20];
    const float* ln_b = (const float*)d_in[21];
    const float* x    = (const float*)d_in[22];
    const int* ei     = (const int*)d_in[23];

    char* p = (char*)d_ws;
    auto alloc = [&](size_t bytes) {
        char* r = p;
        p += (bytes + 255) & ~(size_t)255;
        return r;
    };
    const int MAXE = EE + 8 * NN;  // rows padded to multiple of 8
    float* dinv    = (float*)alloc(NN * 4);
    float* rowsumR = (float*)alloc(NN * 4);
    int* row_ptr   = (int*)alloc((NN + 1) * 4);
    int* counts    = (int*)alloc(NN * 4);
    int* fillc     = (int*)alloc(NN * 4);
    int* colA      = (int*)alloc((size_t)MAXE * 4);
    float* valA    = (float*)alloc((size_t)MAXE * 4);
    float* bnsum   = (float*)alloc((size_t)5 * BB * 1024 * 4);
    float* bnsq    = (float*)alloc((size_t)5 * BB * 1024 * 4);
    float* s_arr   = (float*)alloc((size_t)BB * 1024 * 4);
    float* t_arr   = (float*)alloc((size_t)BB * 1024 * 4);
    unsigned short* wbf = (unsigned short*)alloc((size_t)WO5 * 2);
    unsigned short* bufA = (unsigned short*)alloc((size_t)BB * NN * 1024 * 2);
    unsigned short* bufY = (unsigned short*)alloc((size_t)BB * NN * 1024 * 2);
    const int wofs[5] = {0, WO1, WO2, WO3, WO4};

    // graph build (once per call; padded CSR shared across batch & layers)
    setup_zero<<<(5 * BB * 1024 + 255) / 256, 256, 0, stream>>>(counts, fillc, bnsum, bnsq);
    count_kernel<<<(EE + NN + 255) / 256, 256, 0, stream>>>(ei, counts);
    dinv_kernel<<<(NN + 255) / 256, 256, 0, stream>>>(counts, dinv);
    scan_kernel<<<1, 256, 0, stream>>>(counts, row_ptr);
    fill_pad<<<(EE + 2 * NN + 255) / 256, 256, 0, stream>>>(ei, dinv, row_ptr, counts, fillc, colA, valA);
    rowsum_kernel<<<(NN + 255) / 256, 256, 0, stream>>>(row_ptr, valA, rowsumR);
    conv_all<<<(WO5 + 255) / 256, 256, 0, stream>>>(w[0], w[1], w[2], w[3], w[4], wbf);

    const int Kin[5]  = {64, 256, 512, 1024, 1024};
    const int Fout[5] = {256, 512, 1024, 1024, 1024};
    for (int l = 0; l < 5; ++l) {
        int K = Kin[l], F = Fout[l];
        if (l == 0) {
            agg_f32<<<(NN / 16) * 8, 256, 0, stream>>>(x, row_ptr, colA, valA, bufA);
        } else {
            switch (K) {
                case 256:
                    agg_bf16<256><<<(NN / 8) * 8, 256, 0, stream>>>(bufY, row_ptr, colA, valA, rowsumR, s_arr, t_arr, bufA);
                    break;
                case 512:
                    agg_bf16<512><<<(NN / 4) * 8, 256, 0, stream>>>(bufY, row_ptr, colA, valA, rowsumR, s_arr, t_arr, bufA);
                    break;
                default:
                    agg_bf16<1024><<<(NN / 2) * 8, 256, 0, stream>>>(bufY, row_ptr, colA, valA, rowsumR, s_arr, t_arr, bufA);
                    break;
            }
        }
        gemm_bias_lrelu<<<dim3(BB * NN / 128, F / 128), 256, 0, stream>>>(
            bufA, wbf + wofs[l], bias[l], bufY, bnsum + l * BB * 1024, bnsq + l * BB * 1024, K, F);
        bn_finalize<<<(BB * F + 255) / 256, 256, 0, stream>>>(
            bnsum + l * BB * 1024, bnsq + l * BB * 1024, gam[l], bet[l], s_arr, t_arr, F);
    }
    final_ln<<<BB * NN, 256, 0, stream>>>(bufY, s_arr, t_arr, ln_g, ln_b, (float*)d_out);
}